// Round 7
// baseline (165.369 us; speedup 1.0000x reference)
//
#include <hip/hip_runtime.h>
#include <math.h>

#define N_IMG 128
#define C_DIM 128
#define K_CL  64
#define S_PIX 4096
#define PB    8                 // blocks per image
#define SPB   (S_PIX/PB)        // 512 pixels per block
#define CHK   32                // pixels per chunk
#define NCHK  (SPB/CHK)         // 16
#define NBUF  3                 // X staging buffers (2-deep prefetch)
#define AROW  64                // a' row stride (bf16 elems) = 128B padded
#define APL   (K_CL*AROW)       // one a' plane (elems)

typedef __attribute__((ext_vector_type(8))) short bf16x8;
typedef __attribute__((ext_vector_type(4))) float f32x4;

__device__ __forceinline__ unsigned short f2bf_rn(float v) {
    unsigned u = __float_as_uint(v);
    unsigned r = u + 0x7fffu + ((u >> 16) & 1u);
    return (unsigned short)(r >> 16);
}
__device__ __forceinline__ float bf2f(unsigned short h) {
    return __uint_as_float(((unsigned)h) << 16);
}

// truncation hi/lo split of 8 floats -> two bf16x8, packed via v_perm
__device__ __forceinline__ void cvt8(const float* v, bf16x8& h, bf16x8& l) {
    union { unsigned w[4]; bf16x8 v8; } H, L;
    #pragma unroll
    for (int p = 0; p < 4; ++p) {
        unsigned u0 = __float_as_uint(v[2*p]);
        unsigned u1 = __float_as_uint(v[2*p+1]);
        float r0 = v[2*p]   - __uint_as_float(u0 & 0xffff0000u);
        float r1 = v[2*p+1] - __uint_as_float(u1 & 0xffff0000u);
        H.w[p] = __builtin_amdgcn_perm(u1, u0, 0x07060302u);
        L.w[p] = __builtin_amdgcn_perm(__float_as_uint(r1), __float_as_uint(r0), 0x07060302u);
    }
    h = H.v8; l = L.v8;
}

// async global->LDS, 16B per lane, lane writes lds + lane*16 (linear)
__device__ __forceinline__ void gll16(const float* g, float* l) {
    __builtin_amdgcn_global_load_lds(
        (const __attribute__((address_space(1))) unsigned int*)(g),
        (__attribute__((address_space(3))) unsigned int*)(l),
        16, 0, 0);
}

// a'-tile slot placement: row k (128B, 8 slots of 16B), s-group g8=s>>3 placed at
// slot 4*(k&1) + (g8 ^ ((k>>1)&3))  -> b128 frag reads and writes ~2-way (free)
__device__ __forceinline__ int a_slot(int k, int g8) {
    return 4*(k & 1) + (g8 ^ ((k >> 1) & 3));
}

// ---- kernel 0: W [K][C] fp32 -> pre-fragmented hi/lo bf16 A-fragments ----
// kdim map: MFMA kdim position p=8g+j (g=lane>>4) <-> channel c = 32t + 4j + g
__global__ void k_prep(const float* __restrict__ w, unsigned short* __restrict__ wf) {
    int i = blockIdx.x * 256 + threadIdx.x;          // 8192
    int j = i & 7, l = (i >> 3) & 63, t = (i >> 9) & 3, m = (i >> 11) & 3;
    int k = 16*m + (l & 15);
    int c = 32*t + 4*j + (l >> 4);
    float v = w[k * C_DIM + c];
    unsigned short h = f2bf_rn(v);
    wf[i]        = h;
    wf[8192 + i] = f2bf_rn(v - bf2f(h));
}

// ---- clear kernel: zero vlad accumulator (4MB) + asum (32KB) ----
__global__ void k_clear(float4* __restrict__ out4, float4* __restrict__ asum4) {
    int i = blockIdx.x * 256 + threadIdx.x;
    f32x4 z = (f32x4)0.f;
    if (i < (N_IMG*K_CL*C_DIM)/4) out4[i] = *(float4*)&z;
    if (i < (N_IMG*K_CL)/4)       asum4[i] = *(float4*)&z;
}

// ---- kernel 1: fused GEMM1(MFMA) -> softmax -> GEMM2(MFMA), 2 blocks/CU ----
__global__ __launch_bounds__(512, 4)
void k_main(const float* __restrict__ x,              // [N][C][S]
            const unsigned short* __restrict__ wf,    // [2][16][64][8] bf16 bits
            const float* __restrict__ bias,           // [K]
            float* __restrict__ vlad,                 // [N][K][C] accumulator (= d_out)
            float* __restrict__ asum)                 // [N][K]
{
    __shared__ float Xs[NBUF][C_DIM*CHK];             // 48KB: x chunk tiles, swizzled
    __shared__ unsigned short aS[2*APL];              // 16KB: a' tile (hi/lo planes)
    __shared__ float redS[2][4][16];                  // 512B: softmax sum exchange

    const int tid  = threadIdx.x;
    const int lane = tid & 63;
    const int wid  = tid >> 6;            // 0..7
    const int lc   = lane & 15;
    const int g    = lane >> 4;

    const int p  = wid & 1;               // phase A: px-tile (16 px)
    const int q  = wid >> 1;              // phase A: k-quarter (1 m-tile)
    const int px = p*16 + lc;
    const int cq = wid * 16;              // phase B: c-slice

    const int n  = blockIdx.x / PB;
    const int sp = blockIdx.x % PB;
    const float* xn = x + (size_t)n * (C_DIM * S_PIX) + sp * SPB;

    // ---- W fragments for this wave's k-quarter into REGISTERS (anchored) ----
    bf16x8 Wh[4], Wl[4];
    #pragma unroll
    for (int t = 0; t < 4; ++t) {
        Wh[t] = *(const bf16x8*)&wf[((q*4 + t)*64 + lane)*8];
        Wl[t] = *(const bf16x8*)&wf[((16 + q*4 + t)*64 + lane)*8];
    }
    #pragma unroll
    for (int t = 0; t < 4; ++t) {
        asm volatile("" : "+v"(Wh[t]));
        asm volatile("" : "+v"(Wl[t]));
    }
    f32x4 bias_r = *(const f32x4*)&bias[16*q + 4*g];

    f32x4 accV[4];
    #pragma unroll
    for (int m = 0; m < 4; ++m) accV[m] = (f32x4)0.f;
    float asum_acc[4] = {0.f, 0.f, 0.f, 0.f};

    const int r0 = wid * 16;              // this wave's 16 staged rows

    // stage chunk t into buffer b (2 gll16 per wave; 1KB = 8 rows each)
    auto STAGE = [&](int t, int b) {
        #pragma unroll
        for (int h = 0; h < 2; ++h) {
            int rowbase = r0 + h*8;
            int row = rowbase + (lane >> 3);
            const float* gp = xn + (size_t)row * S_PIX + t*CHK
                            + 4*((lane & 7) ^ (row & 7));
            gll16(gp, &Xs[b][rowbase * 32]);
        }
    };

    // ---- prologue: 2-deep prefetch ----
    STAGE(0, 0);
    STAGE(1, 1);
    asm volatile("s_waitcnt vmcnt(2)" ::: "memory");   // chunk 0 complete
    __builtin_amdgcn_s_barrier();
    __builtin_amdgcn_sched_barrier(0);

    #pragma unroll
    for (int ch = 0; ch < NCHK; ++ch) {
        const int rb = ch % NBUF;
        const float* Xb = &Xs[rb][0];

        // ---- fire-and-forget stage of chunk ch+2 ----
        if (ch + 2 < NCHK) STAGE(ch + 2, (ch + 2) % NBUF);

        // ================= Phase A: GEMM1 (1 m-tile) + softmax =================
        float ss = 0.f;
        f32x4 accL = (f32x4)0.f;
        #pragma unroll
        for (int t = 0; t < 4; ++t) {
            float xv[8];
            #pragma unroll
            for (int j = 0; j < 8; ++j) {
                int c = 32*t + 4*j + g;                       // kdim remap (matches k_prep)
                xv[j] = Xb[c*32 + (((px>>2) ^ (c&7)) << 2) + (px&3)];
            }
            #pragma unroll
            for (int j = 0; j < 8; ++j) ss = fmaf(xv[j], xv[j], ss);
            bf16x8 xh, xl;
            cvt8(xv, xh, xl);
            accL = __builtin_amdgcn_mfma_f32_16x16x32_bf16(Wh[t], xh, accL, 0,0,0);
            accL = __builtin_amdgcn_mfma_f32_16x16x32_bf16(Wh[t], xl, accL, 0,0,0);
            accL = __builtin_amdgcn_mfma_f32_16x16x32_bf16(Wl[t], xh, accL, 0,0,0);
        }
        ss += __shfl_xor(ss, 16); ss += __shfl_xor(ss, 32);
        float rnorm = 1.0f / fmaxf(sqrtf(ss), 1e-12f);

        // no-max softmax: logits bounded (|dot|<=||w_k||~1.15, |b|<=0.5)
        float e[4]; float sm = 0.f;
        #pragma unroll
        for (int jj = 0; jj < 4; ++jj) {
            float t2 = __expf(fmaf(accL[jj], rnorm, bias_r[jj]));
            e[jj] = t2;
            sm += t2;
        }
        sm += __shfl_xor(sm, 16); sm += __shfl_xor(sm, 32);
        if (g == 0) redS[p][q][lc] = sm;

        // ---- B1: red ready (LDS flush only, DMA stays in flight) ----
        asm volatile("s_waitcnt lgkmcnt(0)" ::: "memory");
        __builtin_amdgcn_s_barrier();
        __builtin_amdgcn_sched_barrier(0);

        float S = redS[p][0][lc] + redS[p][1][lc] + redS[p][2][lc] + redS[p][3][lc];
        float coef  = 1.0f / S;
        float coefr = coef * rnorm;

        // write a' hi/lo to aS; accumulate asum (raw a)
        #pragma unroll
        for (int jj = 0; jj < 4; ++jj) {
            float ev = e[jj];
            asum_acc[jj] += ev * coef;
            float ap = ev * coefr;
            unsigned u = __float_as_uint(ap);
            float r = ap - __uint_as_float(u & 0xffff0000u);
            int k = 16*q + 4*g + jj;
            int ix = k*AROW + a_slot(k, px>>3)*8 + (px&7);
            aS[ix]       = (unsigned short)(u >> 16);
            aS[APL + ix] = (unsigned short)(__float_as_uint(r) >> 16);
        }

        // ---- B2: aS ready (LDS flush only) ----
        asm volatile("s_waitcnt lgkmcnt(0)" ::: "memory");
        __builtin_amdgcn_s_barrier();
        __builtin_amdgcn_sched_barrier(0);

        // ================= Phase B: GEMM2 (wave's 16-c slice, K=32) ============
        {
            bf16x8 Ah[4], Al[4];
            #pragma unroll
            for (int m = 0; m < 4; ++m) {
                int k = 16*m + lc;
                int off = k*AROW + a_slot(k, g)*8;
                Ah[m] = *(const bf16x8*)&aS[off];
                Al[m] = *(const bf16x8*)&aS[APL + off];
            }
            int c = cq + lc;
            float4 f0 = *(const float4*)&Xb[c*32 + (((2*g)   ^ (c&7)) << 2)];
            float4 f1 = *(const float4*)&Xb[c*32 + (((2*g+1) ^ (c&7)) << 2)];
            float xv[8] = {f0.x,f0.y,f0.z,f0.w,f1.x,f1.y,f1.z,f1.w};
            bf16x8 xh, xl;
            cvt8(xv, xh, xl);
            #pragma unroll
            for (int m = 0; m < 4; ++m) {
                accV[m] = __builtin_amdgcn_mfma_f32_16x16x32_bf16(Ah[m], xh, accV[m], 0,0,0);
                accV[m] = __builtin_amdgcn_mfma_f32_16x16x32_bf16(Ah[m], xl, accV[m], 0,0,0);
                accV[m] = __builtin_amdgcn_mfma_f32_16x16x32_bf16(Al[m], xh, accV[m], 0,0,0);
            }
        }

        // ---- B3: chunk ch+1 staged data ready; aS + Xs[rb] released ----
        if (ch < NCHK - 1) {
            if (ch + 2 < NCHK) asm volatile("s_waitcnt vmcnt(2)" ::: "memory");
            else               asm volatile("s_waitcnt vmcnt(0)" ::: "memory");
            __builtin_amdgcn_s_barrier();
            __builtin_amdgcn_sched_barrier(0);
        }
    }

    // ---- epilogue: vlad partials -> global atomics ----
    float* vb = vlad + (size_t)n * (K_CL * C_DIM);
    #pragma unroll
    for (int m = 0; m < 4; ++m)
        #pragma unroll
        for (int jj = 0; jj < 4; ++jj)
            atomicAdd(&vb[(16*m + 4*g + jj)*C_DIM + cq + lc], accV[m][jj]);

    // ---- asum: 16-lane butterfly over lc, then atomics ----
    #pragma unroll
    for (int i = 0; i < 4; ++i) {
        float v = asum_acc[i];
        v += __shfl_xor(v, 1); v += __shfl_xor(v, 2);
        v += __shfl_xor(v, 4); v += __shfl_xor(v, 8);
        asum_acc[i] = v;
    }
    if (lc == 0) {
        #pragma unroll
        for (int jj = 0; jj < 4; ++jj)
            atomicAdd(&asum[n*K_CL + 16*q + 4*g + jj], asum_acc[jj]);
    }
}

// ---- kernel 2: subtract a-sum*centroid, intra-norm, global norm ----
__global__ __launch_bounds__(256)
void k_final(float* __restrict__ vlad,          // [N][K*C] in/out (= d_out)
             const float* __restrict__ asum,    // [N][K]
             const float* __restrict__ cent)    // [K][C]
{
    __shared__ float v[K_CL * 132];
    __shared__ float red[K_CL][4];
    __shared__ float rin[K_CL];
    __shared__ float rtot_s;
    const int tid = threadIdx.x;
    const int n   = blockIdx.x;
    float* vb = vlad + (size_t)n * (K_CL * C_DIM);
    const float* as = asum + n * K_CL;

    for (int i = tid; i < K_CL*C_DIM; i += 256) {
        int k = i >> 7, c = i & 127;
        v[k*132 + c] = vb[i] - as[k] * cent[i];
    }
    __syncthreads();
    {
        int k = tid >> 2, p = tid & 3;
        float s2 = 0.f;
        #pragma unroll
        for (int u = 0; u < 32; ++u) { float t = v[k*132 + (u<<2) + p]; s2 = fmaf(t, t, s2); }
        red[k][p] = s2;
    }
    __syncthreads();
    if (tid < K_CL) {
        float s2 = red[tid][0] + red[tid][1] + red[tid][2] + red[tid][3];
        float r  = 1.0f / fmaxf(sqrtf(s2), 1e-12f);
        rin[tid] = r;
        red[tid][0] = s2 * r * r;
    }
    __syncthreads();
    if (tid < 64) {
        float t = red[tid][0];
        t += __shfl_xor(t, 32); t += __shfl_xor(t, 16); t += __shfl_xor(t, 8);
        t += __shfl_xor(t, 4);  t += __shfl_xor(t, 2);  t += __shfl_xor(t, 1);
        if (tid == 0) rtot_s = 1.0f / fmaxf(sqrtf(t), 1e-12f);
    }
    __syncthreads();
    float rt = rtot_s;
    for (int i = tid; i < K_CL*C_DIM; i += 256) {
        vb[i] = v[(i>>7)*132 + (i&127)] * rin[i>>7] * rt;
    }
}

extern "C" void kernel_launch(void* const* d_in, const int* in_sizes, int n_in,
                              void* d_out, int out_size, void* d_ws, size_t ws_size,
                              hipStream_t stream) {
    const float* x    = (const float*)d_in[0];
    const float* w    = (const float*)d_in[1];
    const float* b    = (const float*)d_in[2];
    const float* cent = (const float*)d_in[3];
    float* out = (float*)d_out;
    unsigned short* wf = (unsigned short*)d_ws;           // 32KB
    float* asum = (float*)((char*)d_ws + 32768);          // [N][K]

    k_clear<<<(N_IMG*K_CL*C_DIM/4 + 255)/256, 256, 0, stream>>>(
        (float4*)out, (float4*)asum);
    k_prep<<<32, 256, 0, stream>>>(w, wf);
    k_main<<<N_IMG * PB, 512, 0, stream>>>(x, wf, b, out, asum);
    k_final<<<N_IMG, 256, 0, stream>>>(out, asum, cent);
}